// Round 1
// baseline (3798.627 us; speedup 1.0000x reference)
//
#include <hip/hip_runtime.h>
#include <math.h>

#define BB 32
#define CC 256
#define OO 256
#define HW 56
#define SP (HW*HW)      // 3136
#define KK 4
#define HID 129
#define TEMP 34.0f

// ---------------- Stage 1: mix pooling (avg + max over spatial) ----------------
// grid = B*C blocks, 256 threads; each block reduces one (b,c) plane of 3136 floats.
__global__ __launch_bounds__(256) void pool_kernel(const float* __restrict__ x,
                                                   float* __restrict__ pooled) {
    const int bc = blockIdx.x;            // b*CC + c
    const float4* x4 = (const float4*)(x + (size_t)bc * SP);
    const int tid = threadIdx.x;
    float sum = 0.f, mx = -INFINITY;
    for (int j = tid; j < SP / 4; j += 256) {   // 784 float4
        float4 v = x4[j];
        sum += v.x + v.y + v.z + v.w;
        mx = fmaxf(mx, fmaxf(fmaxf(v.x, v.y), fmaxf(v.z, v.w)));
    }
    __shared__ float ssum[256];
    __shared__ float smax[256];
    ssum[tid] = sum; smax[tid] = mx;
    __syncthreads();
    for (int s = 128; s > 0; s >>= 1) {
        if (tid < s) {
            ssum[tid] += ssum[tid + s];
            smax[tid] = fmaxf(smax[tid], smax[tid + s]);
        }
        __syncthreads();
    }
    if (tid == 0) {
        const int b = bc / CC, c = bc % CC;
        pooled[b * (2 * CC) + c]      = ssum[0] / (float)SP;  // avg
        pooled[b * (2 * CC) + CC + c] = smax[0];              // max
    }
}

// ---------------- Stage 2: attention MLP + softmax + agg bias ----------------
// grid = B blocks, 256 threads.
__global__ __launch_bounds__(256) void attn_kernel(const float* __restrict__ pooled,
                                                   const float* __restrict__ w1,
                                                   const float* __restrict__ w2,
                                                   const float* __restrict__ b2,
                                                   const float* __restrict__ bias_k,
                                                   float* __restrict__ attn,
                                                   float* __restrict__ agg_b) {
    const int b = blockIdx.x;
    const int tid = threadIdx.x;
    __shared__ float p[2 * CC];
    __shared__ float h[HID];
    __shared__ float a[KK];
    for (int i = tid; i < 2 * CC; i += 256) p[i] = pooled[b * 2 * CC + i];
    __syncthreads();
    if (tid < HID) {
        float s = 0.f;
        const float* w1r = w1 + (size_t)tid * (2 * CC);
        for (int c = 0; c < 2 * CC; ++c) s = fmaf(p[c], w1r[c], s);
        h[tid] = fmaxf(s, 0.f);
    }
    __syncthreads();
    if (tid == 0) {
        float lg[KK];
        float m = -INFINITY;
        for (int k = 0; k < KK; ++k) {
            float s = b2[k];
            for (int i = 0; i < HID; ++i) s = fmaf(h[i], w2[k * HID + i], s);
            lg[k] = s / TEMP;
            m = fmaxf(m, lg[k]);
        }
        float den = 0.f;
        for (int k = 0; k < KK; ++k) { lg[k] = expf(lg[k] - m); den += lg[k]; }
        for (int k = 0; k < KK; ++k) { a[k] = lg[k] / den; attn[b * KK + k] = a[k]; }
    }
    __syncthreads();
    if (tid < OO) {
        float s = 0.f;
        #pragma unroll
        for (int k = 0; k < KK; ++k) s = fmaf(a[k], bias_k[k * OO + tid], s);
        agg_b[b * OO + tid] = s;
    }
}

// ---------------- Stage 3: per-sample 3x3 conv (direct, fp32) ----------------
// grid = (14 row-blocks, 32 o-chunks of 8, B). 256 threads; threads 0..223 map to
// a 4-row x 56-col output tile; per channel c: stage 6x56 input rows + 8x9
// attn-combined weights into LDS, then 72 FMAs/thread.
__global__ __launch_bounds__(256) void conv_kernel(const float* __restrict__ x,
                                                   const float* __restrict__ weight,
                                                   const float* __restrict__ attn,
                                                   const float* __restrict__ agg_b,
                                                   float* __restrict__ out) {
    const int rb  = blockIdx.x;   // 0..13 -> rows rb*4 .. rb*4+3
    const int oc  = blockIdx.y;   // 0..31 -> o0 = oc*8
    const int b   = blockIdx.z;
    const int tid = threadIdx.x;
    const int h0  = rb * 4;
    const int o0  = oc * 8;

    __shared__ float xs[6][58];   // rows h0-1..h0+4, cols padded left/right
    __shared__ float ws[8][9];    // combined weights for 8 outputs
    __shared__ float attn_s[KK];

    if (tid < KK) attn_s[tid] = attn[b * KK + tid];
    if (tid < 12) {               // zero the padded columns (never rewritten)
        int r = tid >> 1, side = tid & 1;
        xs[r][side * 57] = 0.f;
    }

    float acc[8];
    #pragma unroll
    for (int i = 0; i < 8; ++i) acc[i] = 0.f;

    const int  lh     = tid / 56;          // 0..3 when active
    const int  w      = tid % 56;
    const bool active = (tid < 224);

    // staging slot precompute: idx1 = tid (always < 336), idx2 = tid + 256 (tid < 80)
    const int r1 = tid / 56,        cc1 = tid % 56;
    const int r2 = (tid + 256) / 56, cc2 = (tid + 256) % 56;
    const int gh1 = h0 - 1 + r1, gh2 = h0 - 1 + r2;
    const bool v1 = (r1 < 6) && (gh1 >= 0) && (gh1 < HW);
    const bool v2 = (tid < 80) && (gh2 >= 0) && (gh2 < HW);
    const float* xrow1 = x + (((size_t)b * CC) * HW + gh1) * HW + cc1;
    const float* xrow2 = x + (((size_t)b * CC) * HW + gh2) * HW + cc2;

    // weight staging: thread tid < 72 handles (o_local = tid/9, uv = tid%9)
    const int ol_s = tid / 9, uv_s = tid % 9;
    const float* wp = weight + ((size_t)(o0 + ol_s) * CC) * 9 + uv_s;  // k=0 base

    __syncthreads();  // attn_s + border zeros visible

    for (int c = 0; c < CC; ++c) {
        // stage x rows (6x56 interior)
        if (r1 < 6) xs[r1][cc1 + 1] = v1 ? xrow1[(size_t)c * SP] : 0.f;
        if (tid < 80) xs[r2][cc2 + 1] = v2 ? xrow2[(size_t)c * SP] : 0.f;
        // stage combined weights
        if (tid < 72) {
            float s = 0.f;
            #pragma unroll
            for (int k = 0; k < KK; ++k)
                s = fmaf(attn_s[k], wp[((size_t)k * OO * CC + c) * 9], s);
            ws[ol_s][uv_s] = s;
        }
        __syncthreads();
        if (active) {
            float xv[9];
            #pragma unroll
            for (int u = 0; u < 3; ++u)
                #pragma unroll
                for (int v = 0; v < 3; ++v)
                    xv[u * 3 + v] = xs[lh + u][w + v];
            #pragma unroll
            for (int ol = 0; ol < 8; ++ol) {
                float s = acc[ol];
                #pragma unroll
                for (int uv = 0; uv < 9; ++uv) s = fmaf(xv[uv], ws[ol][uv], s);
                acc[ol] = s;
            }
        }
        __syncthreads();
    }

    if (active) {
        const int gh = h0 + lh;
        #pragma unroll
        for (int ol = 0; ol < 8; ++ol) {
            const int o = o0 + ol;
            out[(((size_t)b * OO + o) * HW + gh) * HW + w] = acc[ol] + agg_b[b * OO + o];
        }
    }
}

extern "C" void kernel_launch(void* const* d_in, const int* in_sizes, int n_in,
                              void* d_out, int out_size, void* d_ws, size_t ws_size,
                              hipStream_t stream) {
    const float* x      = (const float*)d_in[0];
    const float* weight = (const float*)d_in[1];
    const float* bias_k = (const float*)d_in[2];
    const float* w1     = (const float*)d_in[3];
    const float* w2     = (const float*)d_in[4];
    const float* b2     = (const float*)d_in[5];
    float* out = (float*)d_out;

    float* ws_f   = (float*)d_ws;
    float* pooled = ws_f;                        // B*2C = 16384 floats
    float* attn   = ws_f + BB * 2 * CC;          // B*K  = 128 floats
    float* agg_b  = attn + BB * KK;              // B*O  = 8192 floats

    pool_kernel<<<BB * CC, 256, 0, stream>>>(x, pooled);
    attn_kernel<<<BB, 256, 0, stream>>>(pooled, w1, w2, b2, bias_k, attn, agg_b);
    conv_kernel<<<dim3(14, 32, BB), 256, 0, stream>>>(x, weight, attn, agg_b, out);
}

// Round 2
// 477.850 us; speedup vs baseline: 7.9494x; 7.9494x over previous
//
#include <hip/hip_runtime.h>
#include <math.h>

#define BB 32
#define CC 256
#define OO 256
#define HW 56
#define SP (HW*HW)      // 3136
#define KK 4
#define HID 129
#define TEMP 34.0f

typedef unsigned short u16;
typedef unsigned int uint32;
typedef __attribute__((ext_vector_type(8))) short bf16x8;
typedef __attribute__((ext_vector_type(4))) float f32x4;

__device__ __forceinline__ u16 f2bf(float f) {
    union { float f; uint32 u; } v; v.f = f;
    uint32 r = v.u + 0x7FFF + ((v.u >> 16) & 1);
    return (u16)(r >> 16);
}

// ---------------- Stage 1: mix pooling (avg + max over spatial) ----------------
__global__ __launch_bounds__(256) void pool_kernel(const float* __restrict__ x,
                                                   float* __restrict__ pooled) {
    const int bc = blockIdx.x;            // b*CC + c
    const float4* x4 = (const float4*)(x + (size_t)bc * SP);
    const int tid = threadIdx.x;
    float sum = 0.f, mx = -INFINITY;
    for (int j = tid; j < SP / 4; j += 256) {
        float4 v = x4[j];
        sum += v.x + v.y + v.z + v.w;
        mx = fmaxf(mx, fmaxf(fmaxf(v.x, v.y), fmaxf(v.z, v.w)));
    }
    __shared__ float ssum[256];
    __shared__ float smax[256];
    ssum[tid] = sum; smax[tid] = mx;
    __syncthreads();
    for (int s = 128; s > 0; s >>= 1) {
        if (tid < s) {
            ssum[tid] += ssum[tid + s];
            smax[tid] = fmaxf(smax[tid], smax[tid + s]);
        }
        __syncthreads();
    }
    if (tid == 0) {
        const int b = bc / CC, c = bc % CC;
        pooled[b * (2 * CC) + c]      = ssum[0] / (float)SP;
        pooled[b * (2 * CC) + CC + c] = smax[0];
    }
}

// ---------------- Stage 2: attention MLP + softmax + agg bias ----------------
__global__ __launch_bounds__(256) void attn_kernel(const float* __restrict__ pooled,
                                                   const float* __restrict__ w1,
                                                   const float* __restrict__ w2,
                                                   const float* __restrict__ b2,
                                                   const float* __restrict__ bias_k,
                                                   float* __restrict__ attn,
                                                   float* __restrict__ agg_b) {
    const int b = blockIdx.x;
    const int tid = threadIdx.x;
    __shared__ float p[2 * CC];
    __shared__ float h[HID];
    __shared__ float a[KK];
    for (int i = tid; i < 2 * CC; i += 256) p[i] = pooled[b * 2 * CC + i];
    __syncthreads();
    if (tid < HID) {
        float s = 0.f;
        const float* w1r = w1 + (size_t)tid * (2 * CC);
        for (int c = 0; c < 2 * CC; ++c) s = fmaf(p[c], w1r[c], s);
        h[tid] = fmaxf(s, 0.f);
    }
    __syncthreads();
    if (tid == 0) {
        float lg[KK];
        float m = -INFINITY;
        for (int k = 0; k < KK; ++k) {
            float s = b2[k];
            for (int i = 0; i < HID; ++i) s = fmaf(h[i], w2[k * HID + i], s);
            lg[k] = s / TEMP;
            m = fmaxf(m, lg[k]);
        }
        float den = 0.f;
        for (int k = 0; k < KK; ++k) { lg[k] = expf(lg[k] - m); den += lg[k]; }
        for (int k = 0; k < KK; ++k) { a[k] = lg[k] / den; attn[b * KK + k] = a[k]; }
    }
    __syncthreads();
    if (tid < OO) {
        float s = 0.f;
        #pragma unroll
        for (int k = 0; k < KK; ++k) s = fmaf(a[k], bias_k[k * OO + tid], s);
        agg_b[b * OO + tid] = s;
    }
}

// ---------------- Stage 2b: aggregate weights -> bf16, layout wT[b][uv][o][c] ----
// grid = 256 blocks (one per o), 256 threads (one per c).
__global__ __launch_bounds__(256) void agg_kernel(const float* __restrict__ weight,
                                                  const float* __restrict__ attn,
                                                  u16* __restrict__ wT) {
    const int o = blockIdx.x;
    const int c = threadIdx.x;
    __shared__ float at[BB * KK];
    if (threadIdx.x < BB * KK) at[threadIdx.x] = attn[threadIdx.x];
    __syncthreads();
    float w[KK][9];
    #pragma unroll
    for (int k = 0; k < KK; ++k)
        #pragma unroll
        for (int uv = 0; uv < 9; ++uv)
            w[k][uv] = weight[(size_t)((k * OO + o) * CC + c) * 9 + uv];
    for (int b = 0; b < BB; ++b) {
        const float a0 = at[b*KK+0], a1 = at[b*KK+1], a2 = at[b*KK+2], a3 = at[b*KK+3];
        #pragma unroll
        for (int uv = 0; uv < 9; ++uv) {
            float s = a0 * w[0][uv] + a1 * w[1][uv] + a2 * w[2][uv] + a3 * w[3][uv];
            wT[(size_t)((b * 9 + uv) * OO + o) * CC + c] = f2bf(s);
        }
    }
}

// ---------------- Stage 3: MFMA implicit-GEMM conv ----------------
// Block: 128 o-channels x 224 spatial (4 full rows). 4 waves (2M x 2N), wave
// tile 64 x 112 (M_rep=4, N_rep=7), K-chunks of 32 channels x 9 taps.
// x staged per chunk in LDS [6 rows][58 cols][40 c] bf16 (guards pre-zeroed,
// no masking in the MFMA loop). A-fragments read directly from wT (L2).
#define CPAD 40
__global__ __launch_bounds__(256, 2) void conv_mfma(const float* __restrict__ x,
                                                    const u16* __restrict__ wT,
                                                    const float* __restrict__ agg_b,
                                                    float* __restrict__ out) {
    const int px = blockIdx.x;   // 0..13 (p0 = px*224, exactly 4 image rows)
    const int oy = blockIdx.y;   // 0..1
    const int b  = blockIdx.z;
    const int tid  = threadIdx.x;
    const int lane = tid & 63, wave = tid >> 6;
    const int wm = wave & 1, wn = wave >> 1;
    const int l15 = lane & 15, kg = lane >> 4;
    const int p0 = px * 224;
    const int r0 = px * 4 - 1;   // first staged global row (may be -1)

    __shared__ u16 xs[6 * 58 * CPAD];

    // zero guard columns (col 0 and 57 of every staged row) — stays zero
    if (tid < 48) {
        const int r = tid >> 3, side = (tid >> 2) & 1, oct = tid & 3;
        bf16x8 z = 0;
        *(bf16x8*)&xs[(r * 58 + side * 57) * CPAD + oct * 8] = z;
    }

    // staging map: 336 = 6 rows x 56 cols interior slots
    const int idx2 = tid + 256;
    const int sr1 = tid / 56,  scol1 = tid % 56;
    const int sr2 = idx2 / 56, scol2 = idx2 % 56;
    const int g1 = r0 + sr1, g2 = r0 + sr2;
    const bool v1 = (g1 >= 0) && (g1 < HW);
    const bool act2 = idx2 < 336;
    const bool v2 = act2 && (g2 >= 0) && (g2 < HW);
    const int gp1 = g1 * HW + scol1, gp2 = g2 * HW + scol2;
    const float* xb = x + (size_t)b * CC * SP;

    // B-operand LDS byte offsets per n-fragment (tap offset added later)
    int lds_base[7];
    #pragma unroll
    for (int nf = 0; nf < 7; ++nf) {
        const int n   = wn * 112 + nf * 16 + l15;
        const int rr  = n / 56 + 1;       // row_rel = global_row - r0
        const int col = n % 56;           // p0 % 56 == 0
        lds_base[nf] = (rr * 58 + col + 1) * (2 * CPAD) + kg * 16;
    }

    // A-operand base: wT[b][uv][o][c], o = oy*128 + wm*64 + mf*16 + l15, c = c0 + kg*8
    const u16* wTb = wT + (size_t)b * 9 * OO * CC
                        + (size_t)(oy * 128 + wm * 64 + l15) * CC + kg * 8;

    f32x4 acc[4][7];
    #pragma unroll
    for (int mf = 0; mf < 4; ++mf)
        #pragma unroll
        for (int nf = 0; nf < 7; ++nf)
            acc[mf][nf] = (f32x4)0.f;

    for (int c0 = 0; c0 < CC; c0 += 32) {
        __syncthreads();   // previous chunk's reads done (also covers guard init)
        #pragma unroll
        for (int oct = 0; oct < 4; ++oct) {
            u16 t1[8], t2[8];
            #pragma unroll
            for (int j = 0; j < 8; ++j) {
                const int c = c0 + oct * 8 + j;
                t1[j] = v1 ? f2bf(xb[(size_t)c * SP + gp1]) : (u16)0;
                t2[j] = v2 ? f2bf(xb[(size_t)c * SP + gp2]) : (u16)0;
            }
            *(bf16x8*)&xs[(sr1 * 58 + scol1 + 1) * CPAD + oct * 8] = *(bf16x8*)t1;
            if (act2) *(bf16x8*)&xs[(sr2 * 58 + scol2 + 1) * CPAD + oct * 8] = *(bf16x8*)t2;
        }
        __syncthreads();

        #pragma unroll
        for (int uv = 0; uv < 9; ++uv) {
            const int du = uv / 3 - 1, dv = uv % 3 - 1;
            const int toff = (du * 58 + dv) * (2 * CPAD);
            bf16x8 av[4];
            #pragma unroll
            for (int mf = 0; mf < 4; ++mf)
                av[mf] = *(const bf16x8*)(wTb + (size_t)uv * OO * CC + mf * 16 * CC + c0);
            #pragma unroll
            for (int nf = 0; nf < 7; ++nf) {
                const bf16x8 bv = *(const bf16x8*)((const char*)xs + lds_base[nf] + toff);
                #pragma unroll
                for (int mf = 0; mf < 4; ++mf)
                    acc[mf][nf] = __builtin_amdgcn_mfma_f32_16x16x32_bf16(av[mf], bv, acc[mf][nf], 0, 0, 0);
            }
        }
    }

    // epilogue: D row = (kg*4 + r), col = l15
    const int obase = oy * 128 + wm * 64;
    float* outb = out + (size_t)b * OO * SP;
    #pragma unroll
    for (int mf = 0; mf < 4; ++mf) {
        #pragma unroll
        for (int r = 0; r < 4; ++r) {
            const int o = obase + mf * 16 + kg * 4 + r;
            const float bias = agg_b[b * OO + o];
            #pragma unroll
            for (int nf = 0; nf < 7; ++nf) {
                const int p = p0 + wn * 112 + nf * 16 + l15;
                outb[(size_t)o * SP + p] = acc[mf][nf][r] + bias;
            }
        }
    }
}

extern "C" void kernel_launch(void* const* d_in, const int* in_sizes, int n_in,
                              void* d_out, int out_size, void* d_ws, size_t ws_size,
                              hipStream_t stream) {
    const float* x      = (const float*)d_in[0];
    const float* weight = (const float*)d_in[1];
    const float* bias_k = (const float*)d_in[2];
    const float* w1     = (const float*)d_in[3];
    const float* w2     = (const float*)d_in[4];
    const float* b2     = (const float*)d_in[5];
    float* out = (float*)d_out;

    // workspace layout: wT (bf16, 32*9*256*256 = 18.87M elems = 37.75 MB) first,
    // then fp32 scratch
    u16*   wT     = (u16*)d_ws;
    float* ws_f   = (float*)((char*)d_ws + (size_t)BB * 9 * OO * CC * sizeof(u16));
    float* pooled = ws_f;                        // B*2C
    float* attn   = ws_f + BB * 2 * CC;          // B*K
    float* agg_b  = attn + BB * KK;              // B*O

    pool_kernel<<<BB * CC, 256, 0, stream>>>(x, pooled);
    attn_kernel<<<BB, 256, 0, stream>>>(pooled, w1, w2, b2, bias_k, attn, agg_b);
    agg_kernel<<<OO, 256, 0, stream>>>(weight, attn, wT);
    conv_mfma<<<dim3(14, 2, BB), 256, 0, stream>>>(x, wT, agg_b, out);
}

// Round 3
// 272.152 us; speedup vs baseline: 13.9578x; 1.7558x over previous
//
#include <hip/hip_runtime.h>
#include <math.h>

#define BB 32
#define CC 256
#define OO 256
#define HW 56
#define SP (HW*HW)      // 3136
#define KK 4
#define HID 129
#define TEMP 34.0f
#define CPAD 40         // u16 per LDS slot: 32 data + 8 pad (80 B stride, conflict-free)

typedef unsigned short u16;
typedef unsigned int uint32;
typedef __attribute__((ext_vector_type(8))) short bf16x8;
typedef __attribute__((ext_vector_type(4))) float f32x4;

__device__ __forceinline__ u16 f2bf(float f) {
    union { float f; uint32 u; } v; v.f = f;
    uint32 r = v.u + 0x7FFF + ((v.u >> 16) & 1);
    return (u16)(r >> 16);
}

// ---------------- Stage 1: fused transpose->bf16 + mix pooling ----------------
// grid = (8 cb, 32 b), 256 threads. Block reads 32 fp32 channel planes once:
// writes x_t[b][cb][p][32c] bf16 (coalesced 64B/thread) and per-channel avg/max.
__global__ __launch_bounds__(256) void trans_pool(const float* __restrict__ x,
                                                  u16* __restrict__ xt,
                                                  float* __restrict__ pooled) {
    const int cb = blockIdx.x, b = blockIdx.y;
    const int tid = threadIdx.x;
    const int lane = tid & 63, wave = tid >> 6;
    const float* xp = x + ((size_t)b * CC + cb * 32) * SP;
    u16* xtb = xt + (size_t)(b * 8 + cb) * SP * 32;

    float psum[32], pmax[32];
    #pragma unroll
    for (int c = 0; c < 32; ++c) { psum[c] = 0.f; pmax[c] = -INFINITY; }

    for (int p0 = 0; p0 < SP; p0 += 256) {
        const int p = p0 + tid;
        const bool v = p < SP;
        const int pc = v ? p : (SP - 1);
        u16 ob[32];
        #pragma unroll
        for (int c = 0; c < 32; ++c) {
            const float vv = xp[(size_t)c * SP + pc];
            if (v) { psum[c] += vv; pmax[c] = fmaxf(pmax[c], vv); }
            ob[c] = f2bf(vv);
        }
        if (v) {
            #pragma unroll
            for (int j = 0; j < 4; ++j)
                *(bf16x8*)&xtb[(size_t)p * 32 + j * 8] = *(bf16x8*)&ob[j * 8];
        }
    }
    // full-wave butterfly reduce per channel
    #pragma unroll
    for (int c = 0; c < 32; ++c) {
        #pragma unroll
        for (int off = 32; off >= 1; off >>= 1) {
            psum[c] += __shfl_xor(psum[c], off, 64);
            pmax[c] = fmaxf(pmax[c], __shfl_xor(pmax[c], off, 64));
        }
    }
    __shared__ float ssum[4][32];
    __shared__ float smax[4][32];
    if (lane == 0) {
        #pragma unroll
        for (int c = 0; c < 32; ++c) { ssum[wave][c] = psum[c]; smax[wave][c] = pmax[c]; }
    }
    __syncthreads();
    if (tid < 32) {
        const float s = ssum[0][tid] + ssum[1][tid] + ssum[2][tid] + ssum[3][tid];
        const float m = fmaxf(fmaxf(smax[0][tid], smax[1][tid]),
                              fmaxf(smax[2][tid], smax[3][tid]));
        pooled[b * (2 * CC) + cb * 32 + tid]      = s / (float)SP;
        pooled[b * (2 * CC) + CC + cb * 32 + tid] = m;
    }
}

// ---------------- Stage 2: attention MLP + softmax + agg bias ----------------
__global__ __launch_bounds__(256) void attn_kernel(const float* __restrict__ pooled,
                                                   const float* __restrict__ w1,
                                                   const float* __restrict__ w2,
                                                   const float* __restrict__ b2,
                                                   const float* __restrict__ bias_k,
                                                   float* __restrict__ attn,
                                                   float* __restrict__ agg_b) {
    const int b = blockIdx.x;
    const int tid = threadIdx.x;
    __shared__ float p[2 * CC];
    __shared__ float h[HID];
    __shared__ float a[KK];
    for (int i = tid; i < 2 * CC; i += 256) p[i] = pooled[b * 2 * CC + i];
    __syncthreads();
    if (tid < HID) {
        float s = 0.f;
        const float* w1r = w1 + (size_t)tid * (2 * CC);
        for (int c = 0; c < 2 * CC; ++c) s = fmaf(p[c], w1r[c], s);
        h[tid] = fmaxf(s, 0.f);
    }
    __syncthreads();
    if (tid == 0) {
        float lg[KK];
        float m = -INFINITY;
        for (int k = 0; k < KK; ++k) {
            float s = b2[k];
            for (int i = 0; i < HID; ++i) s = fmaf(h[i], w2[k * HID + i], s);
            lg[k] = s / TEMP;
            m = fmaxf(m, lg[k]);
        }
        float den = 0.f;
        for (int k = 0; k < KK; ++k) { lg[k] = expf(lg[k] - m); den += lg[k]; }
        for (int k = 0; k < KK; ++k) { a[k] = lg[k] / den; attn[b * KK + k] = a[k]; }
    }
    __syncthreads();
    if (tid < OO) {
        float s = 0.f;
        #pragma unroll
        for (int k = 0; k < KK; ++k) s = fmaf(a[k], bias_k[k * OO + tid], s);
        agg_b[b * OO + tid] = s;
    }
}

// ---------------- Stage 2b: aggregate weights -> bf16, layout wT[b][uv][o][c] ----
__global__ __launch_bounds__(256) void agg_kernel(const float* __restrict__ weight,
                                                  const float* __restrict__ attn,
                                                  u16* __restrict__ wT) {
    const int o = blockIdx.x;
    const int c = threadIdx.x;
    __shared__ float at[BB * KK];
    if (threadIdx.x < BB * KK) at[threadIdx.x] = attn[threadIdx.x];
    __syncthreads();
    float w[KK][9];
    #pragma unroll
    for (int k = 0; k < KK; ++k)
        #pragma unroll
        for (int uv = 0; uv < 9; ++uv)
            w[k][uv] = weight[(size_t)((k * OO + o) * CC + c) * 9 + uv];
    for (int b = 0; b < BB; ++b) {
        const float a0 = at[b*KK+0], a1 = at[b*KK+1], a2 = at[b*KK+2], a3 = at[b*KK+3];
        #pragma unroll
        for (int uv = 0; uv < 9; ++uv) {
            float s = a0 * w[0][uv] + a1 * w[1][uv] + a2 * w[2][uv] + a3 * w[3][uv];
            wT[(size_t)((b * 9 + uv) * OO + o) * CC + c] = f2bf(s);
        }
    }
}

// ---------------- Stage 3: MFMA implicit-GEMM conv ----------------
// Block tile: 64 o x 224 p (4 image rows). 4 waves (2M x 2N), wave tile
// 32 x 112 (M_rep=2, N_rep=7). K-chunks of 32 channels x 9 taps.
// x staged from bf16 channel-blocked x_t: 6 vec loads + 6 ds_writes per thread
// per chunk; next chunk's loads issued before compute (T14 split).
__global__ __launch_bounds__(256, 2) void conv_mfma(const u16* __restrict__ xt,
                                                    const u16* __restrict__ wT,
                                                    const float* __restrict__ agg_b,
                                                    float* __restrict__ out) {
    const int px = blockIdx.x;   // 0..13
    const int oy = blockIdx.y;   // 0..3 -> o0 = oy*64
    const int b  = blockIdx.z;
    const int tid  = threadIdx.x;
    const int lane = tid & 63, wave = tid >> 6;
    const int wm = wave & 1, wn = wave >> 1;
    const int l15 = lane & 15, kg = lane >> 4;
    const int p0 = px * 224;
    const int r0 = px * 4 - 1;
    const int pbase = r0 * 56;
    const int b8 = b * 8;

    __shared__ u16 xs[6 * 58 * CPAD];   // 27840 B

    // zero guard columns (slot col 0 and 57 of each staged row) — written once
    if (tid < 48) {
        const int g = tid >> 2, q = tid & 3;
        const int r = g >> 1, side = g & 1;
        bf16x8 z = 0;
        *(bf16x8*)&xs[(r * 58 + side * 57) * CPAD + q * 8] = z;
    }

    // staging map: 336 interior slots x 4 pieces of 16B = 1344 pieces
    int ldsoff[6]; long long goff[6]; bool vld[6], act[6];
    #pragma unroll
    for (int k = 0; k < 6; ++k) {
        const int i = tid + k * 256;
        const int s = i >> 2, q = i & 3;
        const int rrel = s / 56, col = s % 56;
        const int p = pbase + s;
        act[k] = (i < 1344);
        vld[k] = act[k] && (p >= 0) && (p < SP);
        ldsoff[k] = (rrel * 58 + col + 1) * CPAD + q * 8;
        goff[k] = (long long)p * 32 + q * 8;
    }

    // B-operand LDS base (u16 index) per n-fragment
    int lds_base[7];
    #pragma unroll
    for (int nf = 0; nf < 7; ++nf) {
        const int n   = wn * 112 + nf * 16 + l15;
        const int rr  = n / 56 + 1;
        const int col = n % 56;
        lds_base[nf] = (rr * 58 + col + 1) * CPAD + kg * 8;
    }

    // A-operand: wT[b][uv][o][c], o = oy*64 + wm*32 + mf*16 + l15, c = cb*32 + kg*8
    const u16* wTb = wT + (size_t)b * 9 * OO * CC
                        + (size_t)(oy * 64 + wm * 32 + l15) * CC + kg * 8;

    f32x4 acc[2][7];
    #pragma unroll
    for (int mf = 0; mf < 2; ++mf)
        #pragma unroll
        for (int nf = 0; nf < 7; ++nf)
            acc[mf][nf] = (f32x4)0.f;

    // prologue: load chunk 0 into regs
    bf16x8 stg[6];
    {
        const u16* xtb = xt + (size_t)b8 * SP * 32;
        #pragma unroll
        for (int k = 0; k < 6; ++k)
            if (act[k]) stg[k] = vld[k] ? *(const bf16x8*)(xtb + goff[k]) : (bf16x8)0;
    }

    for (int cb = 0; cb < 8; ++cb) {
        __syncthreads();               // prev chunk's LDS reads done (guards for cb=0)
        #pragma unroll
        for (int k = 0; k < 6; ++k)
            if (act[k]) *(bf16x8*)&xs[ldsoff[k]] = stg[k];
        __syncthreads();
        if (cb < 7) {                  // issue next chunk's loads; hide under compute
            const u16* xtb = xt + (size_t)(b8 + cb + 1) * SP * 32;
            #pragma unroll
            for (int k = 0; k < 6; ++k)
                if (act[k]) stg[k] = vld[k] ? *(const bf16x8*)(xtb + goff[k]) : (bf16x8)0;
        }
        const int c0 = cb * 32;
        #pragma unroll
        for (int uv = 0; uv < 9; ++uv) {
            const int du = uv / 3 - 1, dv = uv % 3 - 1;
            const int toff = (du * 58 + dv) * CPAD;
            bf16x8 av[2];
            #pragma unroll
            for (int mf = 0; mf < 2; ++mf)
                av[mf] = *(const bf16x8*)(wTb + (size_t)uv * OO * CC + mf * 16 * CC + c0);
            #pragma unroll
            for (int nf = 0; nf < 7; ++nf) {
                const bf16x8 bv = *(const bf16x8*)&xs[lds_base[nf] + toff];
                #pragma unroll
                for (int mf = 0; mf < 2; ++mf)
                    acc[mf][nf] = __builtin_amdgcn_mfma_f32_16x16x32_bf16(av[mf], bv, acc[mf][nf], 0, 0, 0);
            }
        }
    }

    // epilogue: D row = kg*4 + r (-> o), col = l15 (-> p)
    const int obase = oy * 64 + wm * 32;
    float* outb = out + (size_t)b * OO * SP;
    #pragma unroll
    for (int mf = 0; mf < 2; ++mf) {
        #pragma unroll
        for (int r = 0; r < 4; ++r) {
            const int o = obase + mf * 16 + kg * 4 + r;
            const float bias = agg_b[b * OO + o];
            #pragma unroll
            for (int nf = 0; nf < 7; ++nf) {
                const int p = p0 + wn * 112 + nf * 16 + l15;
                outb[(size_t)o * SP + p] = acc[mf][nf][r] + bias;
            }
        }
    }
}

extern "C" void kernel_launch(void* const* d_in, const int* in_sizes, int n_in,
                              void* d_out, int out_size, void* d_ws, size_t ws_size,
                              hipStream_t stream) {
    const float* x      = (const float*)d_in[0];
    const float* weight = (const float*)d_in[1];
    const float* bias_k = (const float*)d_in[2];
    const float* w1     = (const float*)d_in[3];
    const float* w2     = (const float*)d_in[4];
    const float* b2     = (const float*)d_in[5];
    float* out = (float*)d_out;

    // workspace: x_t bf16 (51.38 MB) | wT bf16 (37.75 MB) | fp32 scratch
    u16* x_t = (u16*)d_ws;
    u16* wT  = x_t + (size_t)BB * 8 * SP * 32;           // 25,690,112 u16
    float* ws_f   = (float*)(wT + (size_t)BB * 9 * OO * CC);
    float* pooled = ws_f;                                // B*2C
    float* attn   = ws_f + BB * 2 * CC;                  // B*K
    float* agg_b  = attn + BB * KK;                      // B*O

    trans_pool<<<dim3(8, BB), 256, 0, stream>>>(x, x_t, pooled);
    attn_kernel<<<BB, 256, 0, stream>>>(pooled, w1, w2, b2, bias_k, attn, agg_b);
    agg_kernel<<<OO, 256, 0, stream>>>(weight, attn, wT);
    conv_mfma<<<dim3(14, 4, BB), 256, 0, stream>>>(x_t, wT, agg_b, out);
}

// Round 4
// 228.771 us; speedup vs baseline: 16.6045x; 1.1896x over previous
//
#include <hip/hip_runtime.h>
#include <math.h>

#define BB 32
#define CC 256
#define OO 256
#define HW 56
#define SP (HW*HW)      // 3136
#define KK 4
#define HID 129
#define TEMP 34.0f
#define CPAD 40         // u16 per LDS slot: 32 data + 8 pad (80 B stride)

typedef unsigned short u16;
typedef unsigned int uint32;
typedef __attribute__((ext_vector_type(8))) short bf16x8;
typedef __attribute__((ext_vector_type(4))) float f32x4;

__device__ __forceinline__ u16 f2bf(float f) {
    union { float f; uint32 u; } v; v.f = f;
    uint32 r = v.u + 0x7FFF + ((v.u >> 16) & 1);
    return (u16)(r >> 16);
}

// ---------------- Stage 1: fused transpose->bf16 + mix pooling ----------------
__global__ __launch_bounds__(256) void trans_pool(const float* __restrict__ x,
                                                  u16* __restrict__ xt,
                                                  float* __restrict__ pooled) {
    const int cb = blockIdx.x, b = blockIdx.y;
    const int tid = threadIdx.x;
    const int lane = tid & 63, wave = tid >> 6;
    const float* xp = x + ((size_t)b * CC + cb * 32) * SP;
    u16* xtb = xt + (size_t)(b * 8 + cb) * SP * 32;

    float psum[32], pmax[32];
    #pragma unroll
    for (int c = 0; c < 32; ++c) { psum[c] = 0.f; pmax[c] = -INFINITY; }

    for (int p0 = 0; p0 < SP; p0 += 256) {
        const int p = p0 + tid;
        const bool v = p < SP;
        const int pc = v ? p : (SP - 1);
        u16 ob[32];
        #pragma unroll
        for (int c = 0; c < 32; ++c) {
            const float vv = xp[(size_t)c * SP + pc];
            if (v) { psum[c] += vv; pmax[c] = fmaxf(pmax[c], vv); }
            ob[c] = f2bf(vv);
        }
        if (v) {
            #pragma unroll
            for (int j = 0; j < 4; ++j)
                *(bf16x8*)&xtb[(size_t)p * 32 + j * 8] = *(bf16x8*)&ob[j * 8];
        }
    }
    #pragma unroll
    for (int c = 0; c < 32; ++c) {
        #pragma unroll
        for (int off = 32; off >= 1; off >>= 1) {
            psum[c] += __shfl_xor(psum[c], off, 64);
            pmax[c] = fmaxf(pmax[c], __shfl_xor(pmax[c], off, 64));
        }
    }
    __shared__ float ssum[4][32];
    __shared__ float smax[4][32];
    if (lane == 0) {
        #pragma unroll
        for (int c = 0; c < 32; ++c) { ssum[wave][c] = psum[c]; smax[wave][c] = pmax[c]; }
    }
    __syncthreads();
    if (tid < 32) {
        const float s = ssum[0][tid] + ssum[1][tid] + ssum[2][tid] + ssum[3][tid];
        const float m = fmaxf(fmaxf(smax[0][tid], smax[1][tid]),
                              fmaxf(smax[2][tid], smax[3][tid]));
        pooled[b * (2 * CC) + cb * 32 + tid]      = s / (float)SP;
        pooled[b * (2 * CC) + CC + cb * 32 + tid] = m;
    }
}

// ---------------- Stage 2: attention MLP + softmax + agg bias ----------------
__global__ __launch_bounds__(256) void attn_kernel(const float* __restrict__ pooled,
                                                   const float* __restrict__ w1,
                                                   const float* __restrict__ w2,
                                                   const float* __restrict__ b2,
                                                   const float* __restrict__ bias_k,
                                                   float* __restrict__ attn,
                                                   float* __restrict__ agg_b) {
    const int b = blockIdx.x;
    const int tid = threadIdx.x;
    __shared__ float p[2 * CC];
    __shared__ float h[HID];
    __shared__ float a[KK];
    for (int i = tid; i < 2 * CC; i += 256) p[i] = pooled[b * 2 * CC + i];
    __syncthreads();
    if (tid < HID) {
        float s = 0.f;
        const float* w1r = w1 + (size_t)tid * (2 * CC);
        for (int c = 0; c < 2 * CC; ++c) s = fmaf(p[c], w1r[c], s);
        h[tid] = fmaxf(s, 0.f);
    }
    __syncthreads();
    if (tid == 0) {
        float lg[KK];
        float m = -INFINITY;
        for (int k = 0; k < KK; ++k) {
            float s = b2[k];
            for (int i = 0; i < HID; ++i) s = fmaf(h[i], w2[k * HID + i], s);
            lg[k] = s / TEMP;
            m = fmaxf(m, lg[k]);
        }
        float den = 0.f;
        for (int k = 0; k < KK; ++k) { lg[k] = expf(lg[k] - m); den += lg[k]; }
        for (int k = 0; k < KK; ++k) { a[k] = lg[k] / den; attn[b * KK + k] = a[k]; }
    }
    __syncthreads();
    if (tid < OO) {
        float s = 0.f;
        #pragma unroll
        for (int k = 0; k < KK; ++k) s = fmaf(a[k], bias_k[k * OO + tid], s);
        agg_b[b * OO + tid] = s;
    }
}

// ---------------- Stage 2b: aggregate weights -> bf16, layout wT[b][uv][o][c] ----
__global__ __launch_bounds__(256) void agg_kernel(const float* __restrict__ weight,
                                                  const float* __restrict__ attn,
                                                  u16* __restrict__ wT) {
    const int o = blockIdx.x;
    const int c = threadIdx.x;
    __shared__ float at[BB * KK];
    if (threadIdx.x < BB * KK) at[threadIdx.x] = attn[threadIdx.x];
    __syncthreads();
    float w[KK][9];
    #pragma unroll
    for (int k = 0; k < KK; ++k)
        #pragma unroll
        for (int uv = 0; uv < 9; ++uv)
            w[k][uv] = weight[(size_t)((k * OO + o) * CC + c) * 9 + uv];
    for (int b = 0; b < BB; ++b) {
        const float a0 = at[b*KK+0], a1 = at[b*KK+1], a2 = at[b*KK+2], a3 = at[b*KK+3];
        #pragma unroll
        for (int uv = 0; uv < 9; ++uv) {
            float s = a0 * w[0][uv] + a1 * w[1][uv] + a2 * w[2][uv] + a3 * w[3][uv];
            wT[(size_t)((b * 9 + uv) * OO + o) * CC + c] = f2bf(s);
        }
    }
}

// ---------------- Stage 3: MFMA implicit-GEMM conv ----------------
// 1-D grid of 896 blocks, XCD-pinned: b = (id&7) + 8*((id>>3)/28) keeps all
// 28 tiles of a sample on one XCD (wT[b]+x_t[b] = 2.8 MB < 4 MB L2).
// Block tile: 128 o x 224 p (4 rows). 4 waves (2M x 2N), wave 64 x 112:
// M_rep=4 (each B-read feeds 4 MFMAs), N_rep=7. Double-buffered LDS staging
// with register prefetch; one barrier per 32-channel chunk.
__global__ __launch_bounds__(256, 2) void conv_mfma(const u16* __restrict__ xt,
                                                    const u16* __restrict__ wT,
                                                    const float* __restrict__ agg_b,
                                                    float* __restrict__ out) {
    const int id   = blockIdx.x;
    const int g    = id >> 3;
    const int b    = (id & 7) + 8 * (g / 28);
    const int tile = g % 28;
    const int px   = tile % 14, oy = tile / 14;
    const int tid  = threadIdx.x;
    const int lane = tid & 63, wave = tid >> 6;
    const int wm = wave & 1, wn = wave >> 1;
    const int l15 = lane & 15, kg = lane >> 4;
    const int p0 = px * 224;
    const int r0 = px * 4 - 1;
    const int pbase = r0 * 56;
    const int b8 = b * 8;

    __shared__ u16 xs[2][6 * 58 * CPAD];   // 2 x 27840 B

    // zero guard columns of both buffers (never rewritten)
    if (tid < 96) {
        const int bufi = tid / 48, t = tid % 48;
        const int gg = t >> 2, q = t & 3;
        const int r = gg >> 1, side = gg & 1;
        bf16x8 z = {};
        *(bf16x8*)&xs[bufi][(r * 58 + side * 57) * CPAD + q * 8] = z;
    }

    // staging map: 336 interior slots x 4 chunks of 16B = 1344 pieces
    int ldsoff[6]; long long goff[6]; bool vld[6], act[6];
    #pragma unroll
    for (int k = 0; k < 6; ++k) {
        const int i = tid + k * 256;
        const int s = i >> 2, q = i & 3;
        const int rrel = s / 56, col = s % 56;
        const int p = pbase + s;
        act[k] = (i < 1344);
        vld[k] = act[k] && (p >= 0) && (p < SP);
        ldsoff[k] = (rrel * 58 + col + 1) * CPAD + q * 8;
        goff[k] = (long long)p * 32 + q * 8;
    }

    // B-operand LDS base (u16 units, within one buffer) per n-fragment
    int lds_base[7];
    #pragma unroll
    for (int nf = 0; nf < 7; ++nf) {
        const int n   = wn * 112 + nf * 16 + l15;
        const int rr  = n / 56 + 1;
        const int col = n % 56;
        lds_base[nf] = (rr * 58 + col + 1) * CPAD + kg * 8;
    }

    // A-operand: wT[b][uv][o][c], o = oy*128 + wm*64 + mf*16 + l15, c = c0 + kg*8
    const u16* wTb = wT + (size_t)b * 9 * OO * CC
                        + (size_t)(oy * 128 + wm * 64 + l15) * CC + kg * 8;

    f32x4 acc[4][7];
    #pragma unroll
    for (int mf = 0; mf < 4; ++mf)
        #pragma unroll
        for (int nf = 0; nf < 7; ++nf)
            acc[mf][nf] = (f32x4)0.f;

    // prologue: chunk 0 -> regs -> buf0
    {
        bf16x8 stg[6];
        const u16* xtb = xt + (size_t)b8 * SP * 32;
        #pragma unroll
        for (int k = 0; k < 6; ++k)
            if (act[k]) stg[k] = vld[k] ? *(const bf16x8*)(xtb + goff[k]) : (bf16x8)0;
        #pragma unroll
        for (int k = 0; k < 6; ++k)
            if (act[k]) *(bf16x8*)&xs[0][ldsoff[k]] = stg[k];
    }
    __syncthreads();

    for (int cb = 0; cb < 8; ++cb) {
        // issue next chunk's loads (latency hides under the 252-MFMA phase)
        bf16x8 nxt[6];
        if (cb < 7) {
            const u16* xtb = xt + (size_t)(b8 + cb + 1) * SP * 32;
            #pragma unroll
            for (int k = 0; k < 6; ++k)
                if (act[k]) nxt[k] = vld[k] ? *(const bf16x8*)(xtb + goff[k]) : (bf16x8)0;
        }

        const u16* xsb = xs[cb & 1];
        const int c0 = cb * 32;
        #pragma unroll
        for (int uv = 0; uv < 9; ++uv) {
            const int du = uv / 3 - 1, dv = uv % 3 - 1;
            const int toff = (du * 58 + dv) * CPAD;
            bf16x8 av[4];
            #pragma unroll
            for (int mf = 0; mf < 4; ++mf)
                av[mf] = *(const bf16x8*)(wTb + (size_t)uv * OO * CC + mf * 16 * CC + c0);
            #pragma unroll
            for (int nf = 0; nf < 7; ++nf) {
                const bf16x8 bv = *(const bf16x8*)&xsb[lds_base[nf] + toff];
                #pragma unroll
                for (int mf = 0; mf < 4; ++mf)
                    acc[mf][nf] = __builtin_amdgcn_mfma_f32_16x16x32_bf16(av[mf], bv, acc[mf][nf], 0, 0, 0);
            }
        }

        // write next chunk into the other buffer
        if (cb < 7) {
            #pragma unroll
            for (int k = 0; k < 6; ++k)
                if (act[k]) *(bf16x8*)&xs[(cb + 1) & 1][ldsoff[k]] = nxt[k];
        }
        __syncthreads();
    }

    // epilogue: D row = kg*4 + r (-> o), col = l15 (-> p)
    const int obase = oy * 128 + wm * 64;
    float* outb = out + (size_t)b * OO * SP;
    #pragma unroll
    for (int mf = 0; mf < 4; ++mf) {
        #pragma unroll
        for (int r = 0; r < 4; ++r) {
            const int o = obase + mf * 16 + kg * 4 + r;
            const float bias = agg_b[b * OO + o];
            #pragma unroll
            for (int nf = 0; nf < 7; ++nf) {
                const int p = p0 + wn * 112 + nf * 16 + l15;
                outb[(size_t)o * SP + p] = acc[mf][nf][r] + bias;
            }
        }
    }
}

extern "C" void kernel_launch(void* const* d_in, const int* in_sizes, int n_in,
                              void* d_out, int out_size, void* d_ws, size_t ws_size,
                              hipStream_t stream) {
    const float* x      = (const float*)d_in[0];
    const float* weight = (const float*)d_in[1];
    const float* bias_k = (const float*)d_in[2];
    const float* w1     = (const float*)d_in[3];
    const float* w2     = (const float*)d_in[4];
    const float* b2     = (const float*)d_in[5];
    float* out = (float*)d_out;

    // workspace: x_t bf16 (51.38 MB) | wT bf16 (37.75 MB) | fp32 scratch
    u16* x_t = (u16*)d_ws;
    u16* wT  = x_t + (size_t)BB * 8 * SP * 32;
    float* ws_f   = (float*)(wT + (size_t)BB * 9 * OO * CC);
    float* pooled = ws_f;
    float* attn   = ws_f + BB * 2 * CC;
    float* agg_b  = attn + BB * KK;

    trans_pool<<<dim3(8, BB), 256, 0, stream>>>(x, x_t, pooled);
    attn_kernel<<<BB, 256, 0, stream>>>(pooled, w1, w2, b2, bias_k, attn, agg_b);
    agg_kernel<<<OO, 256, 0, stream>>>(weight, attn, wT);
    conv_mfma<<<896, 256, 0, stream>>>(x_t, wT, agg_b, out);
}